// Round 8
// baseline (1039.249 us; speedup 1.0000x reference)
//
#include <hip/hip_runtime.h>
#include <stdint.h>

// TernBinLayer: out = binarise(x @ W), x in {-1,+1}, W in {-1,0,+1}.
// Round 7 = round 6 resubmitted verbatim (GPU-acquisition timeout; the
// macro-fixed ping-pong kernel has never executed).
// Structure: lane owns one output column (16 mask VGPRs; ballot->SGPR sign
// words), explicit 2x4-row ping-pong register pipeline with named registers
// + sched_barrier(0) phase pins so 8 row-loads stay in flight per wave.
// Round-3 baseline: VGPR=28 (loads serialized), 343us, HBM 29%, VALU 60%.

#define NROWS 524288
#define DDIM  256
#define BLOCKS 2048
#define ROWS_PER_BLOCK (NROWS / BLOCKS)   // 256 rows -> 64 batches of 4

typedef uint32_t u32;
typedef unsigned long long u64;

// Load a 4-row batch (lane's 16B slice of each row).
#define LOADG(v0, v1, v2, v3, ptr)                                   \
    v0 = *reinterpret_cast<const uint4*>(ptr);                       \
    v1 = *reinterpret_cast<const uint4*>((ptr) + DDIM);              \
    v2 = *reinterpret_cast<const uint4*>((ptr) + 2 * DDIM);          \
    v3 = *reinterpret_cast<const uint4*>((ptr) + 3 * DDIM);

// Process one row held in uint4 xv: ballots -> wave-uniform sign words,
// dot = C - 2*popc((s ^ M) & A), store sign as +-1.0f (binarise(0)=+1).
// Locals use _bl* names: must NOT collide with caller's a*/b* registers.
#define PROC1(xv, optr)                                               \
    {                                                                 \
        const u64 _bl0 = __ballot((int)(xv).x < 0);                   \
        const u64 _bl1 = __ballot((int)(xv).y < 0);                   \
        const u64 _bl2 = __ballot((int)(xv).z < 0);                   \
        const u64 _bl3 = __ballot((int)(xv).w < 0);                   \
        int _p = 0;                                                   \
        _p += __popc(((u32)_bl0         ^ M0) & A0);                  \
        _p += __popc(((u32)(_bl0 >> 32) ^ M1) & A1);                  \
        _p += __popc(((u32)_bl1         ^ M2) & A2);                  \
        _p += __popc(((u32)(_bl1 >> 32) ^ M3) & A3);                  \
        _p += __popc(((u32)_bl2         ^ M4) & A4);                  \
        _p += __popc(((u32)(_bl2 >> 32) ^ M5) & A5);                  \
        _p += __popc(((u32)_bl3         ^ M6) & A6);                  \
        _p += __popc(((u32)(_bl3 >> 32) ^ M7) & A7);                  \
        const int _d = C - 2 * _p;                                    \
        const u32 _o = 0x3f800000u | ((u32)_d & 0x80000000u);         \
        __builtin_nontemporal_store(_o, reinterpret_cast<u32*>(optr));\
    }

// Process a 4-row batch.
#define PROC4(v0, v1, v2, v3, optr)                                  \
    PROC1(v0, (optr));                                               \
    PROC1(v1, (optr) + DDIM);                                        \
    PROC1(v2, (optr) + 2 * DDIM);                                    \
    PROC1(v3, (optr) + 3 * DDIM);

__global__ __launch_bounds__(256, 4)
void ternbin_kernel(const float* __restrict__ x, const float* __restrict__ W,
                    float* __restrict__ out) {
    const int t    = threadIdx.x;     // 0..255
    const int lane = t & 63;
    const int wv   = t >> 6;          // wave id in block = column block
    const int col  = (wv << 6) | lane;

    // ---- Masks for THIS lane's column: 16 VGPRs ----
    // Element k -> word ((k&3)<<1)|(k>>7), bit (k>>2)&31 (matches ballots).
    u32 A0=0,A1=0,A2=0,A3=0,A4=0,A5=0,A6=0,A7=0;
    u32 M0=0,M1=0,M2=0,M3=0,M4=0,M5=0,M6=0,M7=0;
    #pragma unroll 8
    for (int k = 0; k < DDIM; ++k) {
        const float v = W[k * DDIM + col];
        const int   w = ((k & 3) << 1) | (k >> 7);
        const u32 bit = 1u << ((k >> 2) & 31);
        const u32 nz  = (v != 0.0f) ? bit : 0u;
        const u32 ng  = (v <  0.0f) ? bit : 0u;
        switch (w) {
            case 0: A0 |= nz; M0 |= ng; break;
            case 1: A1 |= nz; M1 |= ng; break;
            case 2: A2 |= nz; M2 |= ng; break;
            case 3: A3 |= nz; M3 |= ng; break;
            case 4: A4 |= nz; M4 |= ng; break;
            case 5: A5 |= nz; M5 |= ng; break;
            case 6: A6 |= nz; M6 |= ng; break;
            case 7: A7 |= nz; M7 |= ng; break;
        }
    }
    const int C = __popc(A0) + __popc(A1) + __popc(A2) + __popc(A3)
                + __popc(A4) + __popc(A5) + __popc(A6) + __popc(A7);

    // ---- Main loop: 2x4-row ping-pong register pipeline ----
    const size_t row0 = (size_t)blockIdx.x * ROWS_PER_BLOCK;
    const float* xq = x   + row0 * DDIM + 4 * lane;  // lane's 16B row slice
    float*       oq = out + row0 * DDIM + col;       // lane's output column

    uint4 a0, a1, a2, a3, b0, b1, b2, b3;
    LOADG(a0, a1, a2, a3, xq); xq += 4 * DDIM;       // batch 0
    LOADG(b0, b1, b2, b3, xq); xq += 4 * DDIM;       // batch 1
    __builtin_amdgcn_sched_barrier(0);

    #pragma unroll 1
    for (int k = 0; k < 31; ++k) {
        PROC4(a0, a1, a2, a3, oq); oq += 4 * DDIM;   // batch 2k
        LOADG(a0, a1, a2, a3, xq); xq += 4 * DDIM;   // batch 2k+2
        __builtin_amdgcn_sched_barrier(0);
        PROC4(b0, b1, b2, b3, oq); oq += 4 * DDIM;   // batch 2k+1
        LOADG(b0, b1, b2, b3, xq); xq += 4 * DDIM;   // batch 2k+3
        __builtin_amdgcn_sched_barrier(0);
    }
    PROC4(a0, a1, a2, a3, oq); oq += 4 * DDIM;       // batch 62
    PROC4(b0, b1, b2, b3, oq);                       // batch 63
}

extern "C" void kernel_launch(void* const* d_in, const int* in_sizes, int n_in,
                              void* d_out, int out_size, void* d_ws, size_t ws_size,
                              hipStream_t stream) {
    const float* x = (const float*)d_in[0];
    const float* W = (const float*)d_in[1];
    float* out = (float*)d_out;
    // 2048 blocks x 4 waves; block b owns rows [b*256, (b+1)*256).
    ternbin_kernel<<<BLOCKS, 256, 0, stream>>>(x, W, out);
}

// Round 9
// 982.894 us; speedup vs baseline: 1.0573x; 1.0573x over previous
//
#include <hip/hip_runtime.h>
#include <stdint.h>

// TernBinLayer: out = binarise(x @ W), x in {-1,+1}, W in {-1,0,+1}.
// Round 9 structure: block-level phase pipeline instead of per-wave ILP.
//   Stage:  each wave ballots its 64 rows' sign bits into LDS signs[256][8]
//           (x read ONCE per block, coalesced; no 4x L1-redundant reads).
//   Compute: per row, 2 uniform ds_read_b128 (broadcast, conflict-free)
//           + 16 xor/popc per lane against its column's masks, nt-store.
// 8 blocks/CU resident -> staging blocks' HBM reads overlap other blocks'
// compute phases (TLP pipelining; rounds 6/8 showed per-wave ILP + fences
// REGRESS: 343 -> 450us, VALUBusy 60 -> 27%).

#define NROWS  524288
#define DDIM   256
#define BLOCKS 2048
#define RPB    (NROWS / BLOCKS)   // 256 rows per block
#define RPW    (RPB / 4)          // 64 rows staged per wave

typedef uint32_t u32;
typedef unsigned long long u64;

__global__ __launch_bounds__(256, 8)
void ternbin_kernel(const float* __restrict__ x, const float* __restrict__ W,
                    float* __restrict__ out) {
    // signs[r][w]: sign word w of row r. Element k of a row -> word
    // ((k&3)<<1)|(k>>7), bit (k>>2)&31 (ballot packing: lane holds elems
    // 4l..4l+3; ballot of component j covers all 64 lanes).
    __shared__ u32 signs[RPB][8];   // 8 KB

    const int t    = threadIdx.x;   // 0..255
    const int lane = t & 63;
    const int wv   = t >> 6;
    const int col  = (wv << 6) | lane;

    // ---- Masks for THIS lane's column (16 VGPRs), same layout as signs ----
    u32 A0=0,A1=0,A2=0,A3=0,A4=0,A5=0,A6=0,A7=0;
    u32 M0=0,M1=0,M2=0,M3=0,M4=0,M5=0,M6=0,M7=0;
    #pragma unroll 8
    for (int k = 0; k < DDIM; ++k) {
        const float v = W[k * DDIM + col];
        const int   w = ((k & 3) << 1) | (k >> 7);
        const u32 bit = 1u << ((k >> 2) & 31);
        const u32 nz  = (v != 0.0f) ? bit : 0u;
        const u32 ng  = (v <  0.0f) ? bit : 0u;
        switch (w) {
            case 0: A0 |= nz; M0 |= ng; break;
            case 1: A1 |= nz; M1 |= ng; break;
            case 2: A2 |= nz; M2 |= ng; break;
            case 3: A3 |= nz; M3 |= ng; break;
            case 4: A4 |= nz; M4 |= ng; break;
            case 5: A5 |= nz; M5 |= ng; break;
            case 6: A6 |= nz; M6 |= ng; break;
            case 7: A7 |= nz; M7 |= ng; break;
        }
    }
    const int C = __popc(A0) + __popc(A1) + __popc(A2) + __popc(A3)
                + __popc(A4) + __popc(A5) + __popc(A6) + __popc(A7);

    const size_t row0 = (size_t)blockIdx.x * RPB;

    // ---- Stage phase: wave wv ballots rows [wv*64, wv*64+64) into LDS ----
    {
        const float* xp = x + (row0 + (size_t)wv * RPW) * DDIM + 4 * lane;
        const bool writer  = (lane < 8);
        const bool b2      = (lane & 4) != 0;
        const bool b1      = (lane & 2) != 0;
        const bool b0s     = (lane & 1) != 0;

        #pragma unroll 1
        for (int r = 0; r < RPW; r += 4) {
            // 4 independent coalesced row loads (1 KB each) in flight
            uint4 v0 = *reinterpret_cast<const uint4*>(xp + (size_t)(r + 0) * DDIM);
            uint4 v1 = *reinterpret_cast<const uint4*>(xp + (size_t)(r + 1) * DDIM);
            uint4 v2 = *reinterpret_cast<const uint4*>(xp + (size_t)(r + 2) * DDIM);
            uint4 v3 = *reinterpret_cast<const uint4*>(xp + (size_t)(r + 3) * DDIM);

            #pragma unroll
            for (int i = 0; i < 4; ++i) {
                const uint4 v = (i == 0) ? v0 : (i == 1) ? v1 : (i == 2) ? v2 : v3;
                const u64 q0 = __ballot((int)v.x < 0);
                const u64 q1 = __ballot((int)v.y < 0);
                const u64 q2 = __ballot((int)v.z < 0);
                const u64 q3 = __ballot((int)v.w < 0);
                const u32 w0 = (u32)q0, w1 = (u32)(q0 >> 32);
                const u32 w2 = (u32)q1, w3 = (u32)(q1 >> 32);
                const u32 w4 = (u32)q2, w5 = (u32)(q2 >> 32);
                const u32 w6 = (u32)q3, w7 = (u32)(q3 >> 32);
                // cndmask tree: lane j (j<8) selects word j
                const u32 sel = b2 ? (b1 ? (b0s ? w7 : w6) : (b0s ? w5 : w4))
                                   : (b1 ? (b0s ? w3 : w2) : (b0s ? w1 : w0));
                if (writer) signs[wv * RPW + r + i][lane] = sel;
            }
        }
    }
    __syncthreads();

    // ---- Compute phase: all 256 rows from LDS, lane owns column `col` ----
    float* oq = out + row0 * DDIM + col;
    #pragma unroll 2
    for (int r = 0; r < RPB; ++r) {
        // uniform address -> LDS broadcast, conflict-free
        const uint4 sa = *reinterpret_cast<const uint4*>(&signs[r][0]);
        const uint4 sb = *reinterpret_cast<const uint4*>(&signs[r][4]);
        int p = 0;
        p += __popc((sa.x ^ M0) & A0);
        p += __popc((sa.y ^ M1) & A1);
        p += __popc((sa.z ^ M2) & A2);
        p += __popc((sa.w ^ M3) & A3);
        p += __popc((sb.x ^ M4) & A4);
        p += __popc((sb.y ^ M5) & A5);
        p += __popc((sb.z ^ M6) & A6);
        p += __popc((sb.w ^ M7) & A7);
        const int d = C - 2 * p;                       // exact integer dot
        const u32 o = 0x3f800000u | ((u32)d & 0x80000000u);  // +-1.0f, 0->+1
        __builtin_nontemporal_store(o,
            reinterpret_cast<u32*>(oq + (size_t)r * DDIM));
    }
}

extern "C" void kernel_launch(void* const* d_in, const int* in_sizes, int n_in,
                              void* d_out, int out_size, void* d_ws, size_t ws_size,
                              hipStream_t stream) {
    const float* x = (const float*)d_in[0];
    const float* W = (const float*)d_in[1];
    float* out = (float*)d_out;
    // 2048 blocks x 4 waves; block b owns rows [b*256, (b+1)*256).
    ternbin_kernel<<<BLOCKS, 256, 0, stream>>>(x, W, out);
}